// Round 1
// baseline (418.655 us; speedup 1.0000x reference)
//
#include <hip/hip_runtime.h>
#include <stdint.h>

typedef _Float16 f16;
typedef _Float16 half8 __attribute__((ext_vector_type(8)));
typedef _Float16 half4 __attribute__((ext_vector_type(4)));
typedef float f32x4 __attribute__((ext_vector_type(4)));

static constexpr int Bsz = 2, S = 2048, E = 2048, H = 16, D = 128;
static constexpr int M = Bsz * S;        // 4096
static constexpr int N_QKV = 3 * H * D;  // 6144
static constexpr int HD = H * D;         // 2048

// async global->LDS, 16B per lane. LDS dest must be linear-in-lane (base + lane*16).
__device__ __forceinline__ void gload_lds16(const void* gp, void* lp) {
  __builtin_amdgcn_global_load_lds(
      (const __attribute__((address_space(1))) uint32_t*)(uintptr_t)gp,
      (__attribute__((address_space(3))) uint32_t*)(uint32_t)(uintptr_t)lp,
      16, 0, 0);
}

// ---------- f32 -> f16 cast, 8 elems/thread ----------
__global__ void cast_f32_f16(const float* __restrict__ in, f16* __restrict__ out) {
  size_t i = (size_t)(blockIdx.x * 256 + threadIdx.x) * 8;
  float4 a = *(const float4*)&in[i];
  float4 b = *(const float4*)&in[i + 4];
  half8 h;
  h[0] = (f16)a.x; h[1] = (f16)a.y; h[2] = (f16)a.z; h[3] = (f16)a.w;
  h[4] = (f16)b.x; h[5] = (f16)b.y; h[6] = (f16)b.z; h[7] = (f16)b.w;
  *(half8*)&out[i] = h;
}

// ---------- transpose 2048x2048 f32 [k][n] -> f16 [n][k]; z: 0=wq 1=wk 2=wv 3=wo ----------
__global__ void transpose_cast(const float* __restrict__ wq, const float* __restrict__ wk,
                               const float* __restrict__ wv, const float* __restrict__ wo,
                               f16* __restrict__ wt, f16* __restrict__ wot) {
  __shared__ float tile[32][33];
  int z = blockIdx.z;
  const float* src = (z == 0) ? wq : (z == 1) ? wk : (z == 2) ? wv : wo;
  f16* dst = (z == 3) ? wot : wt + (size_t)z * E * HD;
  int bx = blockIdx.x * 32, by = blockIdx.y * 32;
  int tx = threadIdx.x, ty = threadIdx.y;
#pragma unroll
  for (int r = 0; r < 4; ++r)
    tile[ty + r * 8][tx] = src[(size_t)(by + ty + r * 8) * 2048 + bx + tx];
  __syncthreads();
#pragma unroll
  for (int r = 0; r < 4; ++r)
    dst[(size_t)(bx + ty + r * 8) * 2048 + by + tx] = (f16)tile[tx][ty + r * 8];
}

// ---------- GEMM: A[M][K] f16  x  Bt[N][K] f16  -> C[M][N] (OutT) ----------
// 128x128 tile, BK=32, 4 waves (2x2), 16x16x32 f16 MFMA. m97 structure + chunk XOR swizzle.
template <typename OutT>
__global__ __launch_bounds__(256, 2) void gemm_bt(const f16* __restrict__ A,
                                                  const f16* __restrict__ Bt,
                                                  OutT* __restrict__ C,
                                                  int Mm, int Nn, int Kk) {
  __shared__ f16 As[128 * 32];
  __shared__ f16 Bs[128 * 32];
  const int t = threadIdx.x, l = t & 63;
  const int wm = (t >> 7) & 1, wn = (t >> 6) & 1;
  const int bm = blockIdx.x, bn = blockIdx.y;
  const int lr = l & 15, g = l >> 4;
  const int srow = t >> 2;    // 0..63 staging row
  const int schunk = t & 3;   // 16B chunk within 64B row
  const int scol = ((schunk ^ (srow & 3)) * 8);  // XOR-swizzled source column (elements)
  const size_t abase = (size_t)(bm * 128 + srow) * Kk;
  const size_t bbase = (size_t)(bn * 128 + srow) * Kk;
  f32x4 acc[4][4] = {};
  for (int k0 = 0; k0 < Kk; k0 += 32) {
    __syncthreads();
    gload_lds16(&A[abase + k0 + scol], &As[t * 8]);
    gload_lds16(&A[abase + (size_t)64 * Kk + k0 + scol], &As[2048 + t * 8]);
    gload_lds16(&Bt[bbase + k0 + scol], &Bs[t * 8]);
    gload_lds16(&Bt[bbase + (size_t)64 * Kk + k0 + scol], &Bs[2048 + t * 8]);
    __syncthreads();
    half8 af[4], bf[4];
#pragma unroll
    for (int i = 0; i < 4; ++i) {
      int ra = wm * 64 + i * 16 + lr;
      int rb = wn * 64 + i * 16 + lr;
      af[i] = *(const half8*)&As[ra * 32 + ((g ^ (ra & 3)) * 8)];
      bf[i] = *(const half8*)&Bs[rb * 32 + ((g ^ (rb & 3)) * 8)];
    }
#pragma unroll
    for (int i = 0; i < 4; ++i)
#pragma unroll
      for (int j = 0; j < 4; ++j)
        acc[i][j] = __builtin_amdgcn_mfma_f32_16x16x32_f16(af[i], bf[j], acc[i][j], 0, 0, 0);
  }
  // C/D layout (m89-verified): col = lane&15, row = (lane>>4)*4 + reg
#pragma unroll
  for (int i = 0; i < 4; ++i)
#pragma unroll
    for (int j = 0; j < 4; ++j) {
      int row = bm * 128 + wm * 64 + i * 16 + g * 4;
      int col = bn * 128 + wn * 64 + j * 16 + lr;
#pragma unroll
      for (int r = 0; r < 4; ++r)
        C[(size_t)(row + r) * Nn + col] = (OutT)acc[i][j][r];
    }
}

// ---------- RoPE + split qkv[M][6144] -> Q,K,V [B][H][S][D], rope on q,k ----------
__global__ void rope_split(const f16* __restrict__ qkv, const float* __restrict__ cosb,
                           const float* __restrict__ sinb, f16* __restrict__ Q,
                           f16* __restrict__ Ko, f16* __restrict__ V) {
  int idx = blockIdx.x * 256 + threadIdx.x;  // 2^20 total
  int d4 = idx & 15;
  int h = (idx >> 4) & 15;
  int s = (idx >> 8) & 2047;
  int b = idx >> 19;
  int d = d4 * 4;
  size_t mrow = (size_t)(b * S + s) * N_QKV;
  const f16* q = &qkv[mrow + h * D];
  const f16* k = &qkv[mrow + HD + h * D];
  const f16* v = &qkv[mrow + 2 * HD + h * D];
  size_t ob = ((size_t)(b * H + h) * S + s) * D;
  float4 c1 = *(const float4*)&cosb[s * D + d];
  float4 c2 = *(const float4*)&cosb[s * D + 64 + d];
  float4 s1 = *(const float4*)&sinb[s * D + d];
  float4 s2 = *(const float4*)&sinb[s * D + 64 + d];
  float c1a[4] = {c1.x, c1.y, c1.z, c1.w}, c2a[4] = {c2.x, c2.y, c2.z, c2.w};
  float s1a[4] = {s1.x, s1.y, s1.z, s1.w}, s2a[4] = {s2.x, s2.y, s2.z, s2.w};
  half4 qlo = *(const half4*)&q[d], qhi = *(const half4*)&q[d + 64];
  half4 klo = *(const half4*)&k[d], khi = *(const half4*)&k[d + 64];
  half4 vlo = *(const half4*)&v[d], vhi = *(const half4*)&v[d + 64];
  half4 oql, oqh, okl, okh;
#pragma unroll
  for (int j = 0; j < 4; ++j) {
    float ql = (float)qlo[j], qh = (float)qhi[j];
    float kl = (float)klo[j], kh = (float)khi[j];
    oql[j] = (f16)(ql * c1a[j] - qh * s1a[j]);   // out[d]    = x[d]*cos - x[d+64]*sin
    oqh[j] = (f16)(qh * c2a[j] + ql * s2a[j]);   // out[d+64] = x[d+64]*cos + x[d]*sin
    okl[j] = (f16)(kl * c1a[j] - kh * s1a[j]);
    okh[j] = (f16)(kh * c2a[j] + kl * s2a[j]);
  }
  *(half4*)&Q[ob + d] = oql;  *(half4*)&Q[ob + d + 64] = oqh;
  *(half4*)&Ko[ob + d] = okl; *(half4*)&Ko[ob + d + 64] = okh;
  *(half4*)&V[ob + d] = vlo;  *(half4*)&V[ob + d + 64] = vhi;
}

// ---------- flash attention: Q,K,V [B*H][S][D] f16 -> O [B*S][H*D] f16 ----------
// block = 4 waves x 16 q-rows = 64 q-rows; KV tile = 64; online softmax; no causal mask.
__global__ __launch_bounds__(256, 2) void flash_attn(const f16* __restrict__ Q,
                                                     const f16* __restrict__ K,
                                                     const f16* __restrict__ V,
                                                     f16* __restrict__ O) {
  __shared__ f16 Ks[64 * 128];      // [key][d], d-chunks XOR-swizzled by (row&7)
  __shared__ f16 Vt[128 * 72];      // [d][key], padded stride 72
  __shared__ f16 Ps[4][16 * 72];    // per-wave P tile [qrow][key]
  const int t = threadIdx.x, l = t & 63, w = t >> 6;
  const int lr = l & 15, g = l >> 4;
  const int bid = blockIdx.x;
  const int qt = bid & 31;   // q-tile within sequence
  const int bh = bid >> 5;   // b*H + h
  const size_t base = (size_t)bh * S * D;
  const int q0 = qt * 64 + w * 16;
  half8 qf[4];
#pragma unroll
  for (int kk = 0; kk < 4; ++kk)
    qf[kk] = *(const half8*)&Q[base + (size_t)(q0 + lr) * D + kk * 32 + g * 8];
  f32x4 o[8] = {};
  float m[4], ssum[4];
#pragma unroll
  for (int r = 0; r < 4; ++r) { m[r] = -3.0e38f; ssum[r] = 0.f; }
  for (int kv = 0; kv < S; kv += 64) {
    __syncthreads();  // previous tile fully consumed
    // stage K (16KB contiguous), source pre-swizzled so read-side XOR restores order
#pragma unroll
    for (int rnd = 0; rnd < 4; ++rnd) {
      int c = rnd * 256 + t;
      int krow = c >> 4;
      int kcol8 = (c & 15) ^ (krow & 7);
      gload_lds16(&K[base + (size_t)(kv + krow) * D + kcol8 * 8], &Ks[c * 8]);
    }
    // stage V transposed: lane reads V[kv+l][...], writes Vt[d][l] (2-way banks)
#pragma unroll
    for (int rnd = 0; rnd < 4; ++rnd) {
      int vcol8 = rnd * 4 + w;
      half8 vv = *(const half8*)&V[base + (size_t)(kv + l) * D + vcol8 * 8];
#pragma unroll
      for (int j = 0; j < 8; ++j) Vt[(vcol8 * 8 + j) * 72 + l] = vv[j];
    }
    __syncthreads();  // staging visible (vmcnt+lgkm drained by barrier)
    // QK^T: S[q0+row][kv+col], 4 key-tiles x 4 k-chunks
    f32x4 sc[4] = {};
#pragma unroll
    for (int ni = 0; ni < 4; ++ni) {
      int row = ni * 16 + lr;
#pragma unroll
      for (int kk = 0; kk < 4; ++kk) {
        int lc = kk * 4 + g;
        half8 kf = *(const half8*)&Ks[row * 128 + ((lc ^ (lr & 7)) * 8)];
        sc[ni] = __builtin_amdgcn_mfma_f32_16x16x32_f16(qf[kk], kf, sc[ni], 0, 0, 0);
      }
    }
    // online softmax; rows (l>>4)*4+r live in 16-lane group (l>>4)
    float tmax[4], tsum[4];
#pragma unroll
    for (int r = 0; r < 4; ++r)
      tmax[r] = fmaxf(fmaxf(sc[0][r], sc[1][r]), fmaxf(sc[2][r], sc[3][r]));
#pragma unroll
    for (int off = 1; off < 16; off <<= 1)
#pragma unroll
      for (int r = 0; r < 4; ++r) tmax[r] = fmaxf(tmax[r], __shfl_xor(tmax[r], off));
    float sf[4];
#pragma unroll
    for (int r = 0; r < 4; ++r) {
      float mn = fmaxf(m[r], tmax[r]);
      sf[r] = __expf(m[r] - mn);
      m[r] = mn;
      tsum[r] = 0.f;
    }
#pragma unroll
    for (int ni = 0; ni < 4; ++ni)
#pragma unroll
      for (int r = 0; r < 4; ++r) {
        float p = __expf(sc[ni][r] - m[r]);
        tsum[r] += p;
        Ps[w][(g * 4 + r) * 72 + ni * 16 + lr] = (f16)p;
      }
#pragma unroll
    for (int off = 1; off < 16; off <<= 1)
#pragma unroll
      for (int r = 0; r < 4; ++r) tsum[r] += __shfl_xor(tsum[r], off);
#pragma unroll
    for (int r = 0; r < 4; ++r) ssum[r] = ssum[r] * sf[r] + tsum[r];
#pragma unroll
    for (int dt = 0; dt < 8; ++dt)
#pragma unroll
      for (int r = 0; r < 4; ++r) o[dt][r] *= sf[r];
    __syncthreads();  // Ps write -> read ordering
    // PV: o[q][d] += P[q][key] * V[key][d]
#pragma unroll
    for (int kk2 = 0; kk2 < 2; ++kk2) {
      half8 pf = *(const half8*)&Ps[w][lr * 72 + kk2 * 32 + g * 8];
#pragma unroll
      for (int dt = 0; dt < 8; ++dt) {
        half8 vf = *(const half8*)&Vt[(dt * 16 + lr) * 72 + kk2 * 32 + g * 8];
        o[dt] = __builtin_amdgcn_mfma_f32_16x16x32_f16(pf, vf, o[dt], 0, 0, 0);
      }
    }
  }
  const int b = bh >> 4, h = bh & 15;
#pragma unroll
  for (int dt = 0; dt < 8; ++dt)
#pragma unroll
    for (int r = 0; r < 4; ++r) {
      int srow = q0 + g * 4 + r;
      O[(size_t)(b * S + srow) * HD + h * D + dt * 16 + lr] = (f16)(o[dt][r] / ssum[r]);
    }
}

extern "C" void kernel_launch(void* const* d_in, const int* in_sizes, int n_in,
                              void* d_out, int out_size, void* d_ws, size_t ws_size,
                              hipStream_t stream) {
  (void)in_sizes; (void)n_in; (void)out_size; (void)ws_size;
  const float* hs = (const float*)d_in[0];
  const float* cosb = (const float*)d_in[1];
  const float* sinb = (const float*)d_in[2];
  const float* wq = (const float*)d_in[3];
  const float* wk = (const float*)d_in[4];
  const float* wv = (const float*)d_in[5];
  const float* wo = (const float*)d_in[6];
  float* out = (float*)d_out;
  char* ws = (char*)d_ws;
  // workspace layout (MiB offsets); attn aliases hs16 (hs16 dead after gemm1)
  f16* hs16 = (f16*)(ws);                          // 16M
  f16* attn = (f16*)(ws);                          // 16M (after flash)
  f16* wt   = (f16*)(ws + (16u << 20));            // 24M  [6144][2048]
  f16* wot  = (f16*)(ws + (40u << 20));            // 8M   [2048][2048]
  f16* qkv  = (f16*)(ws + (48u << 20));            // 48M  [4096][6144]
  f16* Qb   = (f16*)(ws + (96u << 20));            // 16M  [32][2048][128]
  f16* Kb   = (f16*)(ws + (112u << 20));           // 16M
  f16* Vb   = (f16*)(ws + (128u << 20));           // 16M

  cast_f32_f16<<<dim3(4096), dim3(256), 0, stream>>>(hs, hs16);
  transpose_cast<<<dim3(64, 64, 4), dim3(32, 8), 0, stream>>>(wq, wk, wv, wo, wt, wot);
  gemm_bt<f16><<<dim3(32, 48), dim3(256), 0, stream>>>(hs16, wt, qkv, M, N_QKV, E);
  rope_split<<<dim3(4096), dim3(256), 0, stream>>>(qkv, cosb, sinb, Qb, Kb, Vb);
  flash_attn<<<dim3(1024), dim3(256), 0, stream>>>(Qb, Kb, Vb, attn);
  gemm_bt<float><<<dim3(32, 16), dim3(256), 0, stream>>>(attn, wot, out, M, E, HD);
}

// Round 3
// 308.439 us; speedup vs baseline: 1.3573x; 1.3573x over previous
//
#include <hip/hip_runtime.h>
#include <stdint.h>

typedef _Float16 f16;
typedef _Float16 half8 __attribute__((ext_vector_type(8)));
typedef _Float16 half4 __attribute__((ext_vector_type(4)));
typedef __fp16 fp16x2 __attribute__((ext_vector_type(2)));
typedef float f32x4 __attribute__((ext_vector_type(4)));
typedef float f32x16 __attribute__((ext_vector_type(16)));
typedef uint32_t u32x4 __attribute__((ext_vector_type(4)));

static constexpr int Bsz = 2, S = 2048, E = 2048, H = 16, D = 128;
static constexpr int M = Bsz * S;        // 4096
static constexpr int N_QKV = 3 * H * D;  // 6144
static constexpr int HD = H * D;         // 2048

// async global->LDS, 16B per lane. LDS dest must be linear-in-lane.
__device__ __forceinline__ void gload_lds16(const void* gp, void* lp) {
  __builtin_amdgcn_global_load_lds(
      (const __attribute__((address_space(1))) uint32_t*)(uintptr_t)gp,
      (__attribute__((address_space(3))) uint32_t*)(uint32_t)(uintptr_t)lp,
      16, 0, 0);
}

__device__ __forceinline__ uint32_t pkrtz(float a, float b) {
  fp16x2 r = __builtin_amdgcn_cvt_pkrtz(a, b);
  return __builtin_bit_cast(uint32_t, r);
}

// ---------- f32 -> f16 cast, 8 elems/thread ----------
__global__ void cast_f32_f16(const float* __restrict__ in, f16* __restrict__ out) {
  size_t i = (size_t)(blockIdx.x * 256 + threadIdx.x) * 8;
  float4 a = *(const float4*)&in[i];
  float4 b = *(const float4*)&in[i + 4];
  half8 h;
  h[0] = (f16)a.x; h[1] = (f16)a.y; h[2] = (f16)a.z; h[3] = (f16)a.w;
  h[4] = (f16)b.x; h[5] = (f16)b.y; h[6] = (f16)b.z; h[7] = (f16)b.w;
  *(half8*)&out[i] = h;
}

// ---------- transpose 2048x2048 f32 [k][n] -> f16 [n][k]; z: 0=wq 1=wk 2=wv 3=wo ----------
__global__ void transpose_cast(const float* __restrict__ wq, const float* __restrict__ wk,
                               const float* __restrict__ wv, const float* __restrict__ wo,
                               f16* __restrict__ wt, f16* __restrict__ wot) {
  __shared__ float tile[32][33];
  int z = blockIdx.z;
  const float* src = (z == 0) ? wq : (z == 1) ? wk : (z == 2) ? wv : wo;
  f16* dst = (z == 3) ? wot : wt + (size_t)z * E * HD;
  int bx = blockIdx.x * 32, by = blockIdx.y * 32;
  int tx = threadIdx.x, ty = threadIdx.y;
#pragma unroll
  for (int r = 0; r < 4; ++r)
    tile[ty + r * 8][tx] = src[(size_t)(by + ty + r * 8) * 2048 + bx + tx];
  __syncthreads();
#pragma unroll
  for (int r = 0; r < 4; ++r)
    dst[(size_t)(bx + ty + r * 8) * 2048 + by + tx] = (f16)tile[tx][ty + r * 8];
}

// ---------- GEMM: A[M][K] f16  x  Bt[N][K] f16  -> C[M][N] (OutT) ----------
template <typename OutT>
__global__ __launch_bounds__(256, 2) void gemm_bt(const f16* __restrict__ A,
                                                  const f16* __restrict__ Bt,
                                                  OutT* __restrict__ C,
                                                  int Mm, int Nn, int Kk) {
  __shared__ f16 As[128 * 32];
  __shared__ f16 Bs[128 * 32];
  const int t = threadIdx.x, l = t & 63;
  const int wm = (t >> 7) & 1, wn = (t >> 6) & 1;
  const int bm = blockIdx.x, bn = blockIdx.y;
  const int lr = l & 15, g = l >> 4;
  const int srow = t >> 2;
  const int schunk = t & 3;
  const int scol = ((schunk ^ (srow & 3)) * 8);
  const size_t abase = (size_t)(bm * 128 + srow) * Kk;
  const size_t bbase = (size_t)(bn * 128 + srow) * Kk;
  f32x4 acc[4][4] = {};
  for (int k0 = 0; k0 < Kk; k0 += 32) {
    __syncthreads();
    gload_lds16(&A[abase + k0 + scol], &As[t * 8]);
    gload_lds16(&A[abase + (size_t)64 * Kk + k0 + scol], &As[2048 + t * 8]);
    gload_lds16(&Bt[bbase + k0 + scol], &Bs[t * 8]);
    gload_lds16(&Bt[bbase + (size_t)64 * Kk + k0 + scol], &Bs[2048 + t * 8]);
    __syncthreads();
    half8 af[4], bf[4];
#pragma unroll
    for (int i = 0; i < 4; ++i) {
      int ra = wm * 64 + i * 16 + lr;
      int rb = wn * 64 + i * 16 + lr;
      af[i] = *(const half8*)&As[ra * 32 + ((g ^ (ra & 3)) * 8)];
      bf[i] = *(const half8*)&Bs[rb * 32 + ((g ^ (rb & 3)) * 8)];
    }
#pragma unroll
    for (int i = 0; i < 4; ++i)
#pragma unroll
      for (int j = 0; j < 4; ++j)
        acc[i][j] = __builtin_amdgcn_mfma_f32_16x16x32_f16(af[i], bf[j], acc[i][j], 0, 0, 0);
  }
#pragma unroll
  for (int i = 0; i < 4; ++i)
#pragma unroll
    for (int j = 0; j < 4; ++j) {
      int row = bm * 128 + wm * 64 + i * 16 + g * 4;
      int col = bn * 128 + wn * 64 + j * 16 + lr;
#pragma unroll
      for (int r = 0; r < 4; ++r)
        C[(size_t)(row + r) * Nn + col] = (OutT)acc[i][j][r];
    }
}

// ---------- RoPE + split qkv[M][6144] -> Q,K [B*H][S][D] ----------
__global__ void rope_split(const f16* __restrict__ qkv, const float* __restrict__ cosb,
                           const float* __restrict__ sinb, f16* __restrict__ Q,
                           f16* __restrict__ Ko) {
  int idx = blockIdx.x * 256 + threadIdx.x;
  int d4 = idx & 15;
  int h = (idx >> 4) & 15;
  int s = (idx >> 8) & 2047;
  int b = idx >> 19;
  int d = d4 * 4;
  size_t mrow = (size_t)(b * S + s) * N_QKV;
  const f16* q = &qkv[mrow + h * D];
  const f16* k = &qkv[mrow + HD + h * D];
  size_t ob = ((size_t)(b * H + h) * S + s) * D;
  float4 c1 = *(const float4*)&cosb[s * D + d];
  float4 c2 = *(const float4*)&cosb[s * D + 64 + d];
  float4 s1 = *(const float4*)&sinb[s * D + d];
  float4 s2 = *(const float4*)&sinb[s * D + 64 + d];
  float c1a[4] = {c1.x, c1.y, c1.z, c1.w}, c2a[4] = {c2.x, c2.y, c2.z, c2.w};
  float s1a[4] = {s1.x, s1.y, s1.z, s1.w}, s2a[4] = {s2.x, s2.y, s2.z, s2.w};
  half4 qlo = *(const half4*)&q[d], qhi = *(const half4*)&q[d + 64];
  half4 klo = *(const half4*)&k[d], khi = *(const half4*)&k[d + 64];
  half4 oql, oqh, okl, okh;
#pragma unroll
  for (int j = 0; j < 4; ++j) {
    float ql = (float)qlo[j], qh = (float)qhi[j];
    float kl = (float)klo[j], kh = (float)khi[j];
    oql[j] = (f16)(ql * c1a[j] - qh * s1a[j]);
    oqh[j] = (f16)(qh * c2a[j] + ql * s2a[j]);
    okl[j] = (f16)(kl * c1a[j] - kh * s1a[j]);
    okh[j] = (f16)(kh * c2a[j] + kl * s2a[j]);
  }
  *(half4*)&Q[ob + d] = oql;  *(half4*)&Q[ob + d + 64] = oqh;
  *(half4*)&Ko[ob + d] = okl; *(half4*)&Ko[ob + d + 64] = okh;
}

// ---------- V transpose: qkv V-part [b,s][h,d] -> VtG [bh][d][s] ----------
__global__ void transpose_v(const f16* __restrict__ qkv, f16* __restrict__ VtG) {
  __shared__ f16 tl[64][136];
  int bid = blockIdx.x;            // 32 bh x 32 s-tiles
  int bh = bid >> 5, st = bid & 31;
  int b = bh >> 4, h = bh & 15;
  int t = threadIdx.x;
  int s0 = st * 64;
#pragma unroll
  for (int rnd = 0; rnd < 4; ++rnd) {
    int row = rnd * 16 + (t >> 4);
    int ch = t & 15;
    half8 v = *(const half8*)&qkv[(size_t)(b * S + s0 + row) * N_QKV + 2 * HD + h * D + ch * 8];
    *(half8*)&tl[row][ch * 8] = v;
  }
  __syncthreads();
#pragma unroll
  for (int rnd = 0; rnd < 4; ++rnd) {
    int d = rnd * 32 + (t >> 3);
    int ch = t & 7;
    half8 v;
#pragma unroll
    for (int j = 0; j < 8; ++j) v[j] = tl[ch * 8 + j][d];
    *(half8*)&VtG[((size_t)bh * D + d) * S + s0 + ch * 8] = v;
  }
}

// ---------- flash attention v2: 32x32x16 MFMA, swapped QK^T and PV ----------
// 4 waves x 32 q-rows = 128 q/block; KVBLK=64; K [64][128] + V^T [128][64] in LDS,
// XOR-swizzled, double-buffered; P^T in registers via cvt_pkrtz + permlane32_swap.
__device__ __forceinline__ void stage_kv(const f16* __restrict__ Kg, const f16* __restrict__ Vg,
                                         f16* KsB, f16* VsB, int t, int kv) {
#pragma unroll
  for (int rnd = 0; rnd < 4; ++rnd) {
    int row = rnd * 16 + (t >> 4);
    int c = t & 15;
    gload_lds16(&Kg[(size_t)(kv + row) * D + ((c ^ (row & 7)) * 8)], &KsB[rnd * 2048 + t * 8]);
  }
#pragma unroll
  for (int rnd = 0; rnd < 4; ++rnd) {
    int row = rnd * 32 + (t >> 3);
    int c = t & 7;
    gload_lds16(&Vg[(size_t)row * S + kv + ((c ^ (row & 7)) * 8)], &VsB[rnd * 2048 + t * 8]);
  }
}

__global__ __launch_bounds__(256, 2) void flash_attn2(const f16* __restrict__ Q,
                                                      const f16* __restrict__ K,
                                                      const f16* __restrict__ Vt,
                                                      f16* __restrict__ O) {
  __shared__ f16 lds[2][16384];  // per buf: Ks[64][128] @0, Vs[128][64] @8192 -> 64KB total
  const int t = threadIdx.x, l = t & 63, w = t >> 6;
  const int c = l & 31, hi = l >> 5;
  int bid = blockIdx.x;
  bid = (bid & 7) * 64 + (bid >> 3);  // bijective XCD chunking (512 = 8*64)
  const int bh = bid >> 4, qt = bid & 15;
  const size_t baseQ = (size_t)bh * S * D;
  const f16* Kg = K + baseQ;
  const f16* Vg = Vt + (size_t)bh * D * S;
  const int q0 = qt * 128 + w * 32;
  half8 qf[8];
#pragma unroll
  for (int dc = 0; dc < 8; ++dc)
    qf[dc] = *(const half8*)&Q[baseQ + (size_t)(q0 + c) * D + dc * 16 + hi * 8];
  f32x16 o[4] = {};
  float m = -3.0e38f, ssum = 0.f;

  stage_kv(Kg, Vg, &lds[0][0], &lds[0][8192], t, 0);
  __syncthreads();

  for (int it = 0; it < S / 64; ++it) {
    const int cur = it & 1;
    const f16* KsB = &lds[cur][0];
    const f16* VsB = &lds[cur][8192];
    if (it + 1 < S / 64) stage_kv(Kg, Vg, &lds[cur ^ 1][0], &lds[cur ^ 1][8192], t, (it + 1) * 64);

    // --- QK^T (swapped): sc = S^T[k][q = c]
    f32x16 s0 = {}, s1 = {};
    __builtin_amdgcn_s_setprio(1);
#pragma unroll
    for (int dc = 0; dc < 8; ++dc) {
      const int r0 = c, r1 = 32 + c;
      half8 kf0 = *(const half8*)&KsB[r0 * 128 + (((2 * dc + hi) ^ (r0 & 7)) * 8)];
      half8 kf1 = *(const half8*)&KsB[r1 * 128 + (((2 * dc + hi) ^ (r1 & 7)) * 8)];
      s0 = __builtin_amdgcn_mfma_f32_32x32x16_f16(kf0, qf[dc], s0, 0, 0, 0);
      s1 = __builtin_amdgcn_mfma_f32_32x32x16_f16(kf1, qf[dc], s1, 0, 0, 0);
    }
    __builtin_amdgcn_s_setprio(0);

    // --- online softmax (stats per q = c; other k-half lives in lane l^32)
    float tm = s0[0];
#pragma unroll
    for (int r = 1; r < 16; ++r) tm = fmaxf(tm, s0[r]);
#pragma unroll
    for (int r = 0; r < 16; ++r) tm = fmaxf(tm, s1[r]);
    tm = fmaxf(tm, __shfl_xor(tm, 32));
    float mn = fmaxf(m, tm);
    float corr = __expf(m - mn);
    m = mn;
    float ts = 0.f;
#pragma unroll
    for (int r = 0; r < 16; ++r) { s0[r] = __expf(s0[r] - mn); ts += s0[r]; }
#pragma unroll
    for (int r = 0; r < 16; ++r) { s1[r] = __expf(s1[r] - mn); ts += s1[r]; }
    ts += __shfl_xor(ts, 32);
    ssum = ssum * corr + ts;
#pragma unroll
    for (int dt = 0; dt < 4; ++dt)
#pragma unroll
      for (int r = 0; r < 16; ++r) o[dt][r] *= corr;

    // --- P^T -> f16 B-fragments: pf[ks] covers k = ks*16 + 8*hi + j
    half8 pf[4];
#pragma unroll
    for (int ks = 0; ks < 4; ++ks) {
      const int B0 = 2 * (ks & 1), B1 = B0 + 1;
      uint32_t X0, X1, Y0, Y1;
      if (ks < 2) {
        X0 = pkrtz(s0[4 * B0 + 0], s0[4 * B0 + 1]);
        X1 = pkrtz(s0[4 * B0 + 2], s0[4 * B0 + 3]);
        Y0 = pkrtz(s0[4 * B1 + 0], s0[4 * B1 + 1]);
        Y1 = pkrtz(s0[4 * B1 + 2], s0[4 * B1 + 3]);
      } else {
        X0 = pkrtz(s1[4 * B0 + 0], s1[4 * B0 + 1]);
        X1 = pkrtz(s1[4 * B0 + 2], s1[4 * B0 + 3]);
        Y0 = pkrtz(s1[4 * B1 + 0], s1[4 * B1 + 1]);
        Y1 = pkrtz(s1[4 * B1 + 2], s1[4 * B1 + 3]);
      }
      asm volatile("v_permlane32_swap_b32 %0, %1" : "+v"(X0), "+v"(Y0));
      asm volatile("v_permlane32_swap_b32 %0, %1" : "+v"(X1), "+v"(Y1));
      u32x4 pw; pw[0] = X0; pw[1] = X1; pw[2] = Y0; pw[3] = Y1;
      pf[ks] = __builtin_bit_cast(half8, pw);
    }

    // --- PV (swapped): o[dt] += V^T[d][k] * P^T[k][q]
    __builtin_amdgcn_s_setprio(1);
#pragma unroll
    for (int dt = 0; dt < 4; ++dt) {
      const int row = dt * 32 + c;
#pragma unroll
      for (int ks = 0; ks < 4; ++ks) {
        half8 vf = *(const half8*)&VsB[row * 64 + (((2 * ks + hi) ^ (row & 7)) * 8)];
        o[dt] = __builtin_amdgcn_mfma_f32_32x32x16_f16(vf, pf[ks], o[dt], 0, 0, 0);
      }
    }
    __builtin_amdgcn_s_setprio(0);
    __syncthreads();  // drains vmcnt (next buf staged) + all waves done with cur
  }

  const float inv = 1.f / ssum;
  const int b = bh >> 4, h = bh & 15;
  const size_t orow = ((size_t)(b * S + q0 + c)) * HD + h * D;
#pragma unroll
  for (int dt = 0; dt < 4; ++dt)
#pragma unroll
    for (int b2 = 0; b2 < 4; ++b2) {
      half4 h4;
#pragma unroll
      for (int a = 0; a < 4; ++a) h4[a] = (f16)(o[dt][4 * b2 + a] * inv);
      *(half4*)&O[orow + dt * 32 + 8 * b2 + 4 * hi] = h4;
    }
}

extern "C" void kernel_launch(void* const* d_in, const int* in_sizes, int n_in,
                              void* d_out, int out_size, void* d_ws, size_t ws_size,
                              hipStream_t stream) {
  (void)in_sizes; (void)n_in; (void)out_size; (void)ws_size;
  const float* hs = (const float*)d_in[0];
  const float* cosb = (const float*)d_in[1];
  const float* sinb = (const float*)d_in[2];
  const float* wq = (const float*)d_in[3];
  const float* wk = (const float*)d_in[4];
  const float* wv = (const float*)d_in[5];
  const float* wo = (const float*)d_in[6];
  float* out = (float*)d_out;
  char* ws = (char*)d_ws;
  f16* hs16 = (f16*)(ws);                 // 16M; attn output aliases after gemm1
  f16* attn = (f16*)(ws);
  f16* wt   = (f16*)(ws + (16u << 20));   // 24M  [6144][2048]
  f16* wot  = (f16*)(ws + (40u << 20));   // 8M   [2048][2048]
  f16* qkv  = (f16*)(ws + (48u << 20));   // 48M  [4096][6144]
  f16* Qb   = (f16*)(ws + (96u << 20));   // 16M  [32][2048][128]
  f16* Kb   = (f16*)(ws + (112u << 20));  // 16M  [32][2048][128]
  f16* VtG  = (f16*)(ws + (128u << 20));  // 16M  [32][128][2048]

  cast_f32_f16<<<dim3(4096), dim3(256), 0, stream>>>(hs, hs16);
  transpose_cast<<<dim3(64, 64, 4), dim3(32, 8), 0, stream>>>(wq, wk, wv, wo, wt, wot);
  gemm_bt<f16><<<dim3(32, 48), dim3(256), 0, stream>>>(hs16, wt, qkv, M, N_QKV, E);
  rope_split<<<dim3(4096), dim3(256), 0, stream>>>(qkv, cosb, sinb, Qb, Kb);
  transpose_v<<<dim3(1024), dim3(256), 0, stream>>>(qkv, VtG);
  flash_attn2<<<dim3(512), dim3(256), 0, stream>>>(Qb, Kb, VtG, attn);
  gemm_bt<float><<<dim3(32, 16), dim3(256), 0, stream>>>(attn, wot, out, M, E, HD);
}